// Round 1
// baseline (204.481 us; speedup 1.0000x reference)
//
#include <hip/hip_runtime.h>

#define CAP 80  // bucket capacity per node; in-degree is Poisson(16), P(>80) ~ 0

static inline size_t alignup(size_t x) { return (x + 255) & ~(size_t)255; }

// ---- build bucketed CSR: cnt[c] = in-degree (excl self-loop); bucket[c*CAP + slot] = src row
__global__ __launch_bounds__(256) void k_fill(const int* __restrict__ colp,
                                              const int* __restrict__ rowp,
                                              int* __restrict__ cnt,
                                              int* __restrict__ bucket, int nE) {
    int e = blockIdx.x * 256 + threadIdx.x;
    if (e >= nE) return;
    int c = colp[e];
    int slot = atomicAdd(&cnt[c], 1);
    if (slot < CAP) bucket[(size_t)c * CAP + slot] = rowp[e];
}

// ---- dis[v] = (deg incl. self-loop)^{-1/2}
__global__ __launch_bounds__(256) void k_dis(const int* __restrict__ cnt,
                                             float* __restrict__ dis, int n) {
    int v = blockIdx.x * 256 + threadIdx.x;
    if (v < n) dis[v] = rsqrtf((float)(cnt[v] + 1));
}

// ---- out[m,:] = (BIAS_RELU ? relu(A[m,:]+bias) : A[m,:]) @ W  * dis[m]
// W staged fully in LDS; 4x4 register tile per thread; float4 LDS reads both sides.
template <int K, int N, int ROWS, bool BIAS_RELU>
__global__ __launch_bounds__(256) void k_gemm(const float* __restrict__ A,
                                              const float* __restrict__ W,
                                              const float* __restrict__ bias,
                                              const float* __restrict__ dis,
                                              float* __restrict__ out, int M) {
    extern __shared__ float sm[];
    float* Wl = sm;           // K*N floats
    float* Al = sm + K * N;   // ROWS*K floats
    const int tid = threadIdx.x;

    const float4* W4 = (const float4*)W;
    for (int i = tid; i < K * N / 4; i += 256)
        *(float4*)&Wl[i * 4] = W4[i];

    const int row0 = blockIdx.x * ROWS;
    const float4* A4 = (const float4*)A;
    for (int i = tid; i < ROWS * (K / 4); i += 256) {
        int r = i / (K / 4), kq = i % (K / 4);
        int gr = row0 + r;
        float4 v = make_float4(0.f, 0.f, 0.f, 0.f);
        if (gr < M) {
            v = A4[(size_t)gr * (K / 4) + kq];
            if (BIAS_RELU) {
                float4 b = ((const float4*)bias)[kq];
                v.x = fmaxf(v.x + b.x, 0.f);
                v.y = fmaxf(v.y + b.y, 0.f);
                v.z = fmaxf(v.z + b.z, 0.f);
                v.w = fmaxf(v.w + b.w, 0.f);
            }
        }
        *(float4*)&Al[r * K + kq * 4] = v;
    }
    __syncthreads();

    const int cg = tid % (N / 4);
    const int rg = tid / (N / 4);
    const int col = cg * 4;
    const int rb = rg * 4;

    float acc[4][4];
#pragma unroll
    for (int i = 0; i < 4; ++i)
#pragma unroll
        for (int j = 0; j < 4; ++j) acc[i][j] = 0.f;

#pragma unroll 2
    for (int k = 0; k < K; k += 4) {
        float4 w0 = *(const float4*)&Wl[(k + 0) * N + col];
        float4 w1 = *(const float4*)&Wl[(k + 1) * N + col];
        float4 w2 = *(const float4*)&Wl[(k + 2) * N + col];
        float4 w3 = *(const float4*)&Wl[(k + 3) * N + col];
#pragma unroll
        for (int i = 0; i < 4; ++i) {
            float4 a = *(const float4*)&Al[(rb + i) * K + k];
            acc[i][0] = fmaf(a.x, w0.x, acc[i][0]);
            acc[i][0] = fmaf(a.y, w1.x, acc[i][0]);
            acc[i][0] = fmaf(a.z, w2.x, acc[i][0]);
            acc[i][0] = fmaf(a.w, w3.x, acc[i][0]);
            acc[i][1] = fmaf(a.x, w0.y, acc[i][1]);
            acc[i][1] = fmaf(a.y, w1.y, acc[i][1]);
            acc[i][1] = fmaf(a.z, w2.y, acc[i][1]);
            acc[i][1] = fmaf(a.w, w3.y, acc[i][1]);
            acc[i][2] = fmaf(a.x, w0.z, acc[i][2]);
            acc[i][2] = fmaf(a.y, w1.z, acc[i][2]);
            acc[i][2] = fmaf(a.z, w2.z, acc[i][2]);
            acc[i][2] = fmaf(a.w, w3.z, acc[i][2]);
            acc[i][3] = fmaf(a.x, w0.w, acc[i][3]);
            acc[i][3] = fmaf(a.y, w1.w, acc[i][3]);
            acc[i][3] = fmaf(a.z, w2.w, acc[i][3]);
            acc[i][3] = fmaf(a.w, w3.w, acc[i][3]);
        }
    }

#pragma unroll
    for (int i = 0; i < 4; ++i) {
        int gr = row0 + rb + i;
        if (gr < M) {
            float s = dis[gr];
            float4 o = make_float4(acc[i][0] * s, acc[i][1] * s, acc[i][2] * s, acc[i][3] * s);
            *(float4*)&out[(size_t)gr * N + col] = o;
        }
    }
}

// ---- out[v,:] = dis[v] * (hs[v,:] + sum_{r in bucket[v]} hs[r,:]) (+ bias)
// D4 = feature dim / 4 (float4 lanes per node). hs already scaled by dis[src].
template <int D4, bool ADD_BIAS>
__global__ __launch_bounds__(256) void k_gather(const float* __restrict__ hs,
                                                const int* __restrict__ bucket,
                                                const int* __restrict__ cnt,
                                                const float* __restrict__ dis,
                                                const float* __restrict__ bias,
                                                float* __restrict__ out, int n) {
    const int npb = 256 / D4;
    int v = blockIdx.x * npb + (int)(threadIdx.x / D4);
    int c = threadIdx.x % D4;
    if (v >= n) return;
    const float4* hs4 = (const float4*)hs;
    size_t base = (size_t)v * D4 + c;
    float4 acc = hs4[base];  // self-loop term (x dis[v] applied at the end)
    int deg = cnt[v];
    if (deg > CAP) deg = CAP;
    const int* bk = bucket + (size_t)v * CAP;
    int e = 0;
    for (; e + 4 <= deg; e += 4) {
        int r0 = bk[e + 0], r1 = bk[e + 1], r2 = bk[e + 2], r3 = bk[e + 3];
        float4 m0 = hs4[(size_t)r0 * D4 + c];
        float4 m1 = hs4[(size_t)r1 * D4 + c];
        float4 m2 = hs4[(size_t)r2 * D4 + c];
        float4 m3 = hs4[(size_t)r3 * D4 + c];
        acc.x += (m0.x + m1.x) + (m2.x + m3.x);
        acc.y += (m0.y + m1.y) + (m2.y + m3.y);
        acc.z += (m0.z + m1.z) + (m2.z + m3.z);
        acc.w += (m0.w + m1.w) + (m2.w + m3.w);
    }
    for (; e < deg; ++e) {
        int r = bk[e];
        float4 m = hs4[(size_t)r * D4 + c];
        acc.x += m.x; acc.y += m.y; acc.z += m.z; acc.w += m.w;
    }
    float s = dis[v];
    acc.x *= s; acc.y *= s; acc.z *= s; acc.w *= s;
    if (ADD_BIAS) {
        float4 b = ((const float4*)bias)[c];
        acc.x += b.x; acc.y += b.y; acc.z += b.z; acc.w += b.w;
    }
    ((float4*)out)[base] = acc;
}

extern "C" void kernel_launch(void* const* d_in, const int* in_sizes, int n_in,
                              void* d_out, int out_size, void* d_ws, size_t ws_size,
                              hipStream_t stream) {
    const float* x  = (const float*)d_in[0];
    const int*   ei = (const int*)d_in[1];
    const float* W1 = (const float*)d_in[2];
    const float* b1 = (const float*)d_in[3];
    const float* W2 = (const float*)d_in[4];
    const float* b2 = (const float*)d_in[5];

    const int Din = 128, Dhid = 128, Dout = 64;
    const int Nn = in_sizes[0] / Din;   // 50000
    const int E  = in_sizes[1] / 2;     // 800000
    const int* rowp = ei;
    const int* colp = ei + E;

    char* ws = (char*)d_ws;
    size_t off = 0;
    int*   cnt    = (int*)(ws + off);   off = alignup(off + (size_t)Nn * 4);
    float* dis    = (float*)(ws + off); off = alignup(off + (size_t)Nn * 4);
    int*   bucket = (int*)(ws + off);   off = alignup(off + (size_t)Nn * CAP * 4);
    float* hs1    = (float*)(ws + off); off = alignup(off + (size_t)Nn * Dhid * 4);
    float* agg1   = (float*)(ws + off); off = alignup(off + (size_t)Nn * Dhid * 4);
    float* hs2    = hs1;  // hs1 is dead after gather1; reuse for layer-2 GEMM output
    float* outp   = (float*)d_out;

    // graph structure (shared by both layers)
    hipMemsetAsync(cnt, 0, (size_t)Nn * 4, stream);
    k_fill<<<(E + 255) / 256, 256, 0, stream>>>(colp, rowp, cnt, bucket, E);
    k_dis<<<(Nn + 255) / 256, 256, 0, stream>>>(cnt, dis, Nn);

    // layer 1: hs1 = (x @ W1) * dis[m]
    constexpr int ROWS1 = 32;
    size_t sm1 = (size_t)(128 * 128 + ROWS1 * 128) * 4;  // 80 KB
    k_gemm<128, 128, ROWS1, false><<<(Nn + ROWS1 - 1) / ROWS1, 256, sm1, stream>>>(
        x, W1, nullptr, dis, hs1, Nn);

    // agg1[v] = dis[v] * (hs1[v] + sum_in hs1[r])   (pre-bias, pre-relu)
    k_gather<32, false><<<(Nn + 7) / 8, 256, 0, stream>>>(
        hs1, bucket, cnt, dis, nullptr, agg1, Nn);

    // layer 2: hs2 = (relu(agg1 + b1) @ W2) * dis[m]
    constexpr int ROWS2 = 64;
    size_t sm2 = (size_t)(128 * 64 + ROWS2 * 128) * 4;   // 64 KB
    k_gemm<128, 64, ROWS2, true><<<(Nn + ROWS2 - 1) / ROWS2, 256, sm2, stream>>>(
        agg1, W2, b1, dis, hs2, Nn);

    // out[v] = dis[v] * (hs2[v] + sum_in hs2[r]) + b2
    k_gather<16, true><<<(Nn + 15) / 16, 256, 0, stream>>>(
        hs2, bucket, cnt, dis, b2, outp, Nn);
}